// Round 6
// baseline (670.975 us; speedup 1.0000x reference)
//
#include <hip/hip_runtime.h>
#include <math.h>

#define NEG_SLOPE 0.2f
#define EPS 1e-16f

__device__ inline float leaky(float v) {
    return v >= 0.0f ? v : NEG_SLOPE * v;
}

// pack two floats into bf16x2 (RNE), low half = first arg
__device__ inline unsigned bf16pack2(float a, float b) {
    unsigned ua = __float_as_uint(a);
    unsigned ub = __float_as_uint(b);
    ua = (ua + 0x7FFFu + ((ua >> 16) & 1u)) >> 16;
    ub = (ub + 0x7FFFu + ((ub >> 16) & 1u)) >> 16;
    return ua | (ub << 16);
}

// ---------------- init: deg=1 (self-loop pre-counted), cursor=0 ----------------
__global__ __launch_bounds__(256) void k_init(int* deg, int* cursor, int N) {
    int gid = blockIdx.x * blockDim.x + threadIdx.x;
    if (gid < N) { deg[gid] = 1; cursor[gid] = 0; }
}

// ---------------- CSR build: histogram of dst ----------------
__global__ __launch_bounds__(256) void k_hist(const int* __restrict__ ei, int* __restrict__ deg, int E) {
    int e = blockIdx.x * blockDim.x + threadIdx.x;
    if (e < E) atomicAdd(&deg[ei[E + e]], 1);
}

// ---------------- CSR build: hierarchical exclusive scan ----------------
__global__ __launch_bounds__(256) void k_scan1(const int* __restrict__ deg, int* __restrict__ rowptr,
                                               int* __restrict__ blocksum, int N) {
    __shared__ int s[256];
    int tid = threadIdx.x;
    int i = blockIdx.x * 256 + tid;
    int v = (i < N) ? deg[i] : 0;
    s[tid] = v;
    __syncthreads();
#pragma unroll
    for (int off = 1; off < 256; off <<= 1) {
        int t = (tid >= off) ? s[tid - off] : 0;
        __syncthreads();
        s[tid] += t;
        __syncthreads();
    }
    if (i < N) rowptr[i] = s[tid] - v;   // exclusive within block
    if (tid == 255) blocksum[blockIdx.x] = s[255];
}

__global__ __launch_bounds__(512) void k_scan2(int* __restrict__ blocksum, int nb) {
    __shared__ int s[512];
    int tid = threadIdx.x;
    int v = (tid < nb) ? blocksum[tid] : 0;
    s[tid] = v;
    __syncthreads();
#pragma unroll
    for (int off = 1; off < 512; off <<= 1) {
        int t = (tid >= off) ? s[tid - off] : 0;
        __syncthreads();
        s[tid] += t;
        __syncthreads();
    }
    if (tid < nb) blocksum[tid] = s[tid] - v;  // exclusive block offsets
}

__global__ __launch_bounds__(256) void k_scan3(int* __restrict__ rowptr, const int* __restrict__ blocksum,
                                               int N, int total) {
    int i = blockIdx.x * blockDim.x + threadIdx.x;
    if (i < N) rowptr[i] += blocksum[i >> 8];
    if (i == 0) rowptr[N] = total;
}

// ---------------- CSR build: fill col with src per dst ----------------
__global__ __launch_bounds__(256) void k_fill(const int* __restrict__ ei, const int* __restrict__ rowptr,
                                              int* __restrict__ cursor, int* __restrict__ col, int E, int N) {
    int e = blockIdx.x * blockDim.x + threadIdx.x;
    if (e >= E + N) return;
    int src, dst;
    if (e < E) { src = ei[e]; dst = ei[E + e]; }
    else       { src = dst = e - E; }
    int pos = atomicAdd(&cursor[dst], 1);
    col[rowptr[dst] + pos] = src;
}

// ---------------- layer 1 GEMM + alpha (register-tiled 4x4, bf16 h1 out) ----
__global__ __launch_bounds__(256) void k_gemm1(const float* __restrict__ x,
                                               const float* __restrict__ W1,
                                               const float* __restrict__ a_src,
                                               const float* __restrict__ a_dst,
                                               unsigned* __restrict__ h1bf,
                                               float* __restrict__ as1,
                                               float* __restrict__ ad1, int N) {
    int tid = threadIdx.x;
    int c4 = tid & 31;             // cols c4*4 .. c4*4+3
    int rq = tid >> 5;             // 0..7
    int r0 = blockIdx.x * 32 + rq * 4;
    if (r0 >= N) return;
    const float* xr0 = x + (size_t)min(r0 + 0, N - 1) * 64;
    const float* xr1 = x + (size_t)min(r0 + 1, N - 1) * 64;
    const float* xr2 = x + (size_t)min(r0 + 2, N - 1) * 64;
    const float* xr3 = x + (size_t)min(r0 + 3, N - 1) * 64;
    const float4* w4 = (const float4*)W1;   // [64][32] float4

    float4 acc0 = {0,0,0,0}, acc1 = {0,0,0,0}, acc2 = {0,0,0,0}, acc3 = {0,0,0,0};
#pragma unroll
    for (int k4 = 0; k4 < 16; ++k4) {
        float4 xa = *(const float4*)(xr0 + k4 * 4);
        float4 xb = *(const float4*)(xr1 + k4 * 4);
        float4 xc = *(const float4*)(xr2 + k4 * 4);
        float4 xd = *(const float4*)(xr3 + k4 * 4);
        float4 w0 = w4[(k4 * 4 + 0) * 32 + c4];
        float4 w1 = w4[(k4 * 4 + 1) * 32 + c4];
        float4 w2 = w4[(k4 * 4 + 2) * 32 + c4];
        float4 w3 = w4[(k4 * 4 + 3) * 32 + c4];
        acc0.x += xa.x*w0.x + xa.y*w1.x + xa.z*w2.x + xa.w*w3.x;
        acc0.y += xa.x*w0.y + xa.y*w1.y + xa.z*w2.y + xa.w*w3.y;
        acc0.z += xa.x*w0.z + xa.y*w1.z + xa.z*w2.z + xa.w*w3.z;
        acc0.w += xa.x*w0.w + xa.y*w1.w + xa.z*w2.w + xa.w*w3.w;
        acc1.x += xb.x*w0.x + xb.y*w1.x + xb.z*w2.x + xb.w*w3.x;
        acc1.y += xb.x*w0.y + xb.y*w1.y + xb.z*w2.y + xb.w*w3.y;
        acc1.z += xb.x*w0.z + xb.y*w1.z + xb.z*w2.z + xb.w*w3.z;
        acc1.w += xb.x*w0.w + xb.y*w1.w + xb.z*w2.w + xb.w*w3.w;
        acc2.x += xc.x*w0.x + xc.y*w1.x + xc.z*w2.x + xc.w*w3.x;
        acc2.y += xc.x*w0.y + xc.y*w1.y + xc.z*w2.y + xc.w*w3.y;
        acc2.z += xc.x*w0.z + xc.y*w1.z + xc.z*w2.z + xc.w*w3.z;
        acc2.w += xc.x*w0.w + xc.y*w1.w + xc.z*w2.w + xc.w*w3.w;
        acc3.x += xd.x*w0.x + xd.y*w1.x + xd.z*w2.x + xd.w*w3.x;
        acc3.y += xd.x*w0.y + xd.y*w1.y + xd.z*w2.y + xd.w*w3.y;
        acc3.z += xd.x*w0.z + xd.y*w1.z + xd.z*w2.z + xd.w*w3.z;
        acc3.w += xd.x*w0.w + xd.y*w1.w + xd.z*w2.w + xd.w*w3.w;
    }

    // store h1 tile as packed bf16 (row = 64 uints; this thread owns 2 uints)
    uint2 p0 = { bf16pack2(acc0.x, acc0.y), bf16pack2(acc0.z, acc0.w) };
    uint2 p1 = { bf16pack2(acc1.x, acc1.y), bf16pack2(acc1.z, acc1.w) };
    uint2 p2 = { bf16pack2(acc2.x, acc2.y), bf16pack2(acc2.z, acc2.w) };
    uint2 p3 = { bf16pack2(acc3.x, acc3.y), bf16pack2(acc3.z, acc3.w) };
    uint2* hb = (uint2*)h1bf;
    if (r0 + 0 < N) hb[(size_t)(r0 + 0) * 32 + c4] = p0;
    if (r0 + 1 < N) hb[(size_t)(r0 + 1) * 32 + c4] = p1;
    if (r0 + 2 < N) hb[(size_t)(r0 + 2) * 32 + c4] = p2;
    if (r0 + 3 < N) hb[(size_t)(r0 + 3) * 32 + c4] = p3;

    // attention dots from fp32 accumulators (precision unchanged)
    float4 av = ((const float4*)a_src)[c4];
    float4 dv = ((const float4*)a_dst)[c4];
    float s0 = acc0.x*av.x + acc0.y*av.y + acc0.z*av.z + acc0.w*av.w;
    float s1 = acc1.x*av.x + acc1.y*av.y + acc1.z*av.z + acc1.w*av.w;
    float s2 = acc2.x*av.x + acc2.y*av.y + acc2.z*av.z + acc2.w*av.w;
    float s3 = acc3.x*av.x + acc3.y*av.y + acc3.z*av.z + acc3.w*av.w;
    float d0 = acc0.x*dv.x + acc0.y*dv.y + acc0.z*dv.z + acc0.w*dv.w;
    float d1 = acc1.x*dv.x + acc1.y*dv.y + acc1.z*dv.z + acc1.w*dv.w;
    float d2 = acc2.x*dv.x + acc2.y*dv.y + acc2.z*dv.z + acc2.w*dv.w;
    float d3 = acc3.x*dv.x + acc3.y*dv.y + acc3.z*dv.z + acc3.w*dv.w;
#pragma unroll
    for (int off = 1; off < 8; off <<= 1) {
        s0 += __shfl_xor(s0, off); s1 += __shfl_xor(s1, off);
        s2 += __shfl_xor(s2, off); s3 += __shfl_xor(s3, off);
        d0 += __shfl_xor(d0, off); d1 += __shfl_xor(d1, off);
        d2 += __shfl_xor(d2, off); d3 += __shfl_xor(d3, off);
    }
    if ((c4 & 7) == 0) {
        int h = c4 >> 3;
        if (r0 + 0 < N) { as1[(r0 + 0) * 4 + h] = s0; ad1[(r0 + 0) * 4 + h] = d0; }
        if (r0 + 1 < N) { as1[(r0 + 1) * 4 + h] = s1; ad1[(r0 + 1) * 4 + h] = d1; }
        if (r0 + 2 < N) { as1[(r0 + 2) * 4 + h] = s2; ad1[(r0 + 2) * 4 + h] = d2; }
        if (r0 + 3 < N) { as1[(r0 + 3) * 4 + h] = s3; ad1[(r0 + 3) * 4 + h] = d3; }
    }
}

// ---------------- layer 1 fused gather (paired features, bf16 h1) ----------
// one 64-lane wave per dst; lane owns features 2*lane, 2*lane+1 (same head
// h = lane>>4) -> ONE leaky/exp + ONE as1 load + ONE dword h1 load per edge.
__global__ __launch_bounds__(256) void k_gather1(const int* __restrict__ rowptr,
                                                 const int* __restrict__ col,
                                                 const float* __restrict__ as1,
                                                 const float* __restrict__ ad1,
                                                 const unsigned* __restrict__ h1bf,
                                                 const float* __restrict__ b1,
                                                 float* __restrict__ out1, int N) {
    int tid = threadIdx.x;
    int wid = (blockIdx.x * blockDim.x + tid) >> 6;
    if (wid >= N) return;
    int lane = tid & 63;
    int dst = wid;
    int start = rowptr[dst], end = rowptr[dst + 1];
    float4 ad = *(const float4*)(ad1 + (size_t)dst * 4);

    // pass 1: per-head max, edge-strided across lanes
    float m0 = -INFINITY, m1 = -INFINITY, m2 = -INFINITY, m3 = -INFINITY;
    for (int j = start + lane; j < end; j += 64) {
        int src = col[j];
        float4 a = *(const float4*)(as1 + (size_t)src * 4);
        m0 = fmaxf(m0, leaky(a.x + ad.x));
        m1 = fmaxf(m1, leaky(a.y + ad.y));
        m2 = fmaxf(m2, leaky(a.z + ad.z));
        m3 = fmaxf(m3, leaky(a.w + ad.w));
    }
#pragma unroll
    for (int off = 32; off; off >>= 1) {
        m0 = fmaxf(m0, __shfl_xor(m0, off));
        m1 = fmaxf(m1, __shfl_xor(m1, off));
        m2 = fmaxf(m2, __shfl_xor(m2, off));
        m3 = fmaxf(m3, __shfl_xor(m3, off));
    }

    int h = lane >> 4;                       // 0..3
    float mh  = (h == 0) ? m0 : (h == 1) ? m1 : (h == 2) ? m2 : m3;
    float adh = (h == 0) ? ad.x : (h == 1) ? ad.y : (h == 2) ? ad.z : ad.w;

    // pass 2: feature-parallel accumulation; lane handles f=2*lane, 2*lane+1
    float acc0 = 0.0f, acc1 = 0.0f, den = 0.0f;
    bool den_lane = (lane & 15) == 0;        // lanes 0,16,32,48 own head denoms
    for (int j = start; j < end; ++j) {
        int src = col[j];
        float ex = __expf(leaky(as1[src * 4 + h] + adh) - mh);
        unsigned u = h1bf[(size_t)src * 64 + lane];
        acc0 += ex * __uint_as_float(u << 16);
        acc1 += ex * __uint_as_float(u & 0xFFFF0000u);
        if (den_lane) den += ex;
    }
    float dh = __shfl(den, h << 4);          // broadcast my head's denom

    float inv = 1.0f / (dh + EPS);
    int f0 = 2 * lane;
    float vA = acc0 * inv + b1[f0];
    float vB = acc1 * inv + b1[f0 + 1];
    float2 o;
    o.x = vA > 0.0f ? vA : 0.0f;
    o.y = vB > 0.0f ? vB : 0.0f;
    *(float2*)(out1 + (size_t)dst * 128 + f0) = o;
}

// ---------------- layer 2 GEMM + alpha (register-tiled 4x4) ----------------
__global__ __launch_bounds__(256) void k_gemm2(const float* __restrict__ out1,
                                               const float* __restrict__ W2,
                                               const float* __restrict__ a_src,
                                               const float* __restrict__ a_dst,
                                               float* __restrict__ h2,
                                               float* __restrict__ as2,
                                               float* __restrict__ ad2, int N) {
    int tid = threadIdx.x;
    int c4 = tid & 7;              // cols c4*4 .. c4*4+3
    int rq = tid >> 3;             // 0..31
    int r0 = blockIdx.x * 128 + rq * 4;
    if (r0 >= N) return;
    const float* xr0 = out1 + (size_t)min(r0 + 0, N - 1) * 128;
    const float* xr1 = out1 + (size_t)min(r0 + 1, N - 1) * 128;
    const float* xr2 = out1 + (size_t)min(r0 + 2, N - 1) * 128;
    const float* xr3 = out1 + (size_t)min(r0 + 3, N - 1) * 128;
    const float4* w4 = (const float4*)W2;   // [128][8] float4

    float4 acc0 = {0,0,0,0}, acc1 = {0,0,0,0}, acc2 = {0,0,0,0}, acc3 = {0,0,0,0};
#pragma unroll 8
    for (int k4 = 0; k4 < 32; ++k4) {
        float4 xa = *(const float4*)(xr0 + k4 * 4);
        float4 xb = *(const float4*)(xr1 + k4 * 4);
        float4 xc = *(const float4*)(xr2 + k4 * 4);
        float4 xd = *(const float4*)(xr3 + k4 * 4);
        float4 w0 = w4[(k4 * 4 + 0) * 8 + c4];
        float4 w1 = w4[(k4 * 4 + 1) * 8 + c4];
        float4 w2 = w4[(k4 * 4 + 2) * 8 + c4];
        float4 w3 = w4[(k4 * 4 + 3) * 8 + c4];
        acc0.x += xa.x*w0.x + xa.y*w1.x + xa.z*w2.x + xa.w*w3.x;
        acc0.y += xa.x*w0.y + xa.y*w1.y + xa.z*w2.y + xa.w*w3.y;
        acc0.z += xa.x*w0.z + xa.y*w1.z + xa.z*w2.z + xa.w*w3.z;
        acc0.w += xa.x*w0.w + xa.y*w1.w + xa.z*w2.w + xa.w*w3.w;
        acc1.x += xb.x*w0.x + xb.y*w1.x + xb.z*w2.x + xb.w*w3.x;
        acc1.y += xb.x*w0.y + xb.y*w1.y + xb.z*w2.y + xb.w*w3.y;
        acc1.z += xb.x*w0.z + xb.y*w1.z + xb.z*w2.z + xb.w*w3.z;
        acc1.w += xb.x*w0.w + xb.y*w1.w + xb.z*w2.w + xb.w*w3.w;
        acc2.x += xc.x*w0.x + xc.y*w1.x + xc.z*w2.x + xc.w*w3.x;
        acc2.y += xc.x*w0.y + xc.y*w1.y + xc.z*w2.y + xc.w*w3.y;
        acc2.z += xc.x*w0.z + xc.y*w1.z + xc.z*w2.z + xc.w*w3.z;
        acc2.w += xc.x*w0.w + xc.y*w1.w + xc.z*w2.w + xc.w*w3.w;
        acc3.x += xd.x*w0.x + xd.y*w1.x + xd.z*w2.x + xd.w*w3.x;
        acc3.y += xd.x*w0.y + xd.y*w1.y + xd.z*w2.y + xd.w*w3.y;
        acc3.z += xd.x*w0.z + xd.y*w1.z + xd.z*w2.z + xd.w*w3.z;
        acc3.w += xd.x*w0.w + xd.y*w1.w + xd.z*w2.w + xd.w*w3.w;
    }

    float4* h4 = (float4*)h2;
    if (r0 + 0 < N) h4[(size_t)(r0 + 0) * 8 + c4] = acc0;
    if (r0 + 1 < N) h4[(size_t)(r0 + 1) * 8 + c4] = acc1;
    if (r0 + 2 < N) h4[(size_t)(r0 + 2) * 8 + c4] = acc2;
    if (r0 + 3 < N) h4[(size_t)(r0 + 3) * 8 + c4] = acc3;

    float4 av = ((const float4*)a_src)[c4];
    float4 dv = ((const float4*)a_dst)[c4];
    float s0 = acc0.x*av.x + acc0.y*av.y + acc0.z*av.z + acc0.w*av.w;
    float s1 = acc1.x*av.x + acc1.y*av.y + acc1.z*av.z + acc1.w*av.w;
    float s2 = acc2.x*av.x + acc2.y*av.y + acc2.z*av.z + acc2.w*av.w;
    float s3 = acc3.x*av.x + acc3.y*av.y + acc3.z*av.z + acc3.w*av.w;
    float d0 = acc0.x*dv.x + acc0.y*dv.y + acc0.z*dv.z + acc0.w*dv.w;
    float d1 = acc1.x*dv.x + acc1.y*dv.y + acc1.z*dv.z + acc1.w*dv.w;
    float d2 = acc2.x*dv.x + acc2.y*dv.y + acc2.z*dv.z + acc2.w*dv.w;
    float d3 = acc3.x*dv.x + acc3.y*dv.y + acc3.z*dv.z + acc3.w*dv.w;
#pragma unroll
    for (int off = 1; off < 8; off <<= 1) {
        s0 += __shfl_xor(s0, off); s1 += __shfl_xor(s1, off);
        s2 += __shfl_xor(s2, off); s3 += __shfl_xor(s3, off);
        d0 += __shfl_xor(d0, off); d1 += __shfl_xor(d1, off);
        d2 += __shfl_xor(d2, off); d3 += __shfl_xor(d3, off);
    }
    if (c4 == 0) {
        if (r0 + 0 < N) { as2[r0 + 0] = s0; ad2[r0 + 0] = d0; }
        if (r0 + 1 < N) { as2[r0 + 1] = s1; ad2[r0 + 1] = d1; }
        if (r0 + 2 < N) { as2[r0 + 2] = s2; ad2[r0 + 2] = d2; }
        if (r0 + 3 < N) { as2[r0 + 3] = s3; ad2[r0 + 3] = d3; }
    }
}

// ---------------- layer 2 fused gather + final linear (chunked shfl) -------
__global__ __launch_bounds__(256) void k_gather2(const int* __restrict__ rowptr,
                                                 const int* __restrict__ col,
                                                 const float* __restrict__ as2,
                                                 const float* __restrict__ ad2,
                                                 const float* __restrict__ h2,
                                                 const float* __restrict__ b2,
                                                 const float* __restrict__ W_lin,
                                                 const float* __restrict__ b_lin,
                                                 float* __restrict__ out, int N) {
    int tid = threadIdx.x;
    int swid = (blockIdx.x * blockDim.x + tid) >> 5;
    if (swid >= N) return;
    int l32 = tid & 31;
    int dst = swid;
    int start = rowptr[dst], end = rowptr[dst + 1];
    float adv = ad2[dst];

    // pass 1: max, edge-strided across 32 lanes
    float m = -INFINITY;
    for (int j = start + l32; j < end; j += 32) {
        m = fmaxf(m, leaky(as2[col[j]] + adv));
    }
#pragma unroll
    for (int off = 16; off; off >>= 1) m = fmaxf(m, __shfl_xor(m, off, 32));

    // pass 2: chunked broadcast accumulation
    float acc = 0.0f, den = 0.0f;
    for (int base = start; base < end; base += 32) {
        int j = base + l32;
        float ex = 0.0f;
        int mysrc = 0;
        if (j < end) {
            mysrc = col[j];
            ex = __expf(leaky(as2[mysrc] + adv) - m);
            den += ex;
        }
        int cnt = min(32, end - base);
        for (int t = 0; t < cnt; ++t) {
            float exb = __shfl(ex, t, 32);
            int srcb = __shfl(mysrc, t, 32);
            acc += exb * h2[(size_t)srcb * 32 + l32];
        }
    }
#pragma unroll
    for (int off = 16; off; off >>= 1) den += __shfl_xor(den, off, 32);

    float v = acc / (den + EPS) + b2[l32];
    v = v > 0.0f ? v : 0.0f;

    // final linear: dot(v, W_lin) + b_lin
    float w = v * W_lin[l32];
#pragma unroll
    for (int off = 16; off; off >>= 1) w += __shfl_xor(w, off, 32);
    if (l32 == 0) out[dst] = w + b_lin[0];
}

extern "C" void kernel_launch(void* const* d_in, const int* in_sizes, int n_in,
                              void* d_out, int out_size, void* d_ws, size_t ws_size,
                              hipStream_t stream) {
    const float* x      = (const float*)d_in[0];
    const int*   ei     = (const int*)d_in[1];
    // d_in[2] = batch (unused)
    const float* W1     = (const float*)d_in[3];
    const float* a_src1 = (const float*)d_in[4];
    const float* a_dst1 = (const float*)d_in[5];
    const float* b1     = (const float*)d_in[6];
    const float* W2     = (const float*)d_in[7];
    const float* a_src2 = (const float*)d_in[8];
    const float* a_dst2 = (const float*)d_in[9];
    const float* b2     = (const float*)d_in[10];
    const float* W_lin  = (const float*)d_in[11];
    const float* b_lin  = (const float*)d_in[12];
    float* out = (float*)d_out;

    const int N = in_sizes[0] / 64;
    const int E = in_sizes[1] / 2;
    const int T = E + N;               // total edges incl. self-loops
    const int NB = (N + 255) / 256;    // scan blocks

    // workspace layout
    float* ws = (float*)d_ws;
    size_t off = 0;
    float* h1reg = ws + off; off += (size_t)N * 128;  // h1bf uses half; h2 (fp32 N*32) reuses it in layer 2
    float* out1 = ws + off; off += (size_t)N * 128;
    float* as1  = ws + off; off += (size_t)N * 4;
    float* ad1  = ws + off; off += (size_t)N * 4;
    float* as2  = ws + off; off += (size_t)N;
    float* ad2  = ws + off; off += (size_t)N;
    int* deg      = (int*)(ws + off); off += (size_t)N;
    int* cursor   = (int*)(ws + off); off += (size_t)N;
    int* rowptr   = (int*)(ws + off); off += (size_t)N + 4;
    int* blocksum = (int*)(ws + off); off += 1024;
    int* colarr   = (int*)(ws + off); off += (size_t)T;
    unsigned* h1bf = (unsigned*)h1reg;   // N*64 uints (bf16x2)
    float* h2 = h1reg;                   // layer-1 h1 dead after k_gather1

    const int B = 256;
    auto blocks = [](size_t t, int b) { return (unsigned)((t + b - 1) / b); };

    // CSR build
    k_init <<<blocks(N, B), B, 0, stream>>>(deg, cursor, N);
    k_hist <<<blocks(E, B), B, 0, stream>>>(ei, deg, E);
    k_scan1<<<NB, 256, 0, stream>>>(deg, rowptr, blocksum, N);
    k_scan2<<<1, 512, 0, stream>>>(blocksum, NB);
    k_scan3<<<blocks(N, B), B, 0, stream>>>(rowptr, blocksum, N, T);
    k_fill <<<blocks(T, B), B, 0, stream>>>(ei, rowptr, cursor, colarr, E, N);

    // layer 1
    k_gemm1  <<<(unsigned)((N + 31) / 32), B, 0, stream>>>(x, W1, a_src1, a_dst1, h1bf, as1, ad1, N);
    k_gather1<<<blocks((size_t)N * 64, B), B, 0, stream>>>(rowptr, colarr, as1, ad1, h1bf, b1, out1, N);

    // layer 2 (+ fused final linear)
    k_gemm2  <<<(unsigned)((N + 127) / 128), B, 0, stream>>>(out1, W2, a_src2, a_dst2, h2, as2, ad2, N);
    k_gather2<<<blocks((size_t)N * 32, B), B, 0, stream>>>(rowptr, colarr, as2, ad2, h2, b2, W_lin, b_lin, out, N);
}

// Round 7
// 545.388 us; speedup vs baseline: 1.2303x; 1.2303x over previous
//
#include <hip/hip_runtime.h>
#include <math.h>

#define NEG_SLOPE 0.2f
#define EPS 1e-16f

__device__ inline float leaky(float v) {
    return v >= 0.0f ? v : NEG_SLOPE * v;
}

// pack two floats into bf16x2 (RNE), low half = first arg
__device__ inline unsigned bf16pack2(float a, float b) {
    unsigned ua = __float_as_uint(a);
    unsigned ub = __float_as_uint(b);
    ua = (ua + 0x7FFFu + ((ua >> 16) & 1u)) >> 16;
    ub = (ub + 0x7FFFu + ((ub >> 16) & 1u)) >> 16;
    return ua | (ub << 16);
}

__device__ inline float bf16lo(unsigned u) { return __uint_as_float(u << 16); }
__device__ inline float bf16hi(unsigned u) { return __uint_as_float(u & 0xFFFF0000u); }

// ---------------- init: deg=1 (self-loop pre-counted), cursor=0 ----------------
__global__ __launch_bounds__(256) void k_init(int* deg, int* cursor, int N) {
    int gid = blockIdx.x * blockDim.x + threadIdx.x;
    if (gid < N) { deg[gid] = 1; cursor[gid] = 0; }
}

// ---------------- CSR build: histogram of dst ----------------
__global__ __launch_bounds__(256) void k_hist(const int* __restrict__ ei, int* __restrict__ deg, int E) {
    int e = blockIdx.x * blockDim.x + threadIdx.x;
    if (e < E) atomicAdd(&deg[ei[E + e]], 1);
}

// ---------------- CSR build: hierarchical exclusive scan ----------------
__global__ __launch_bounds__(256) void k_scan1(const int* __restrict__ deg, int* __restrict__ rowptr,
                                               int* __restrict__ blocksum, int N) {
    __shared__ int s[256];
    int tid = threadIdx.x;
    int i = blockIdx.x * 256 + tid;
    int v = (i < N) ? deg[i] : 0;
    s[tid] = v;
    __syncthreads();
#pragma unroll
    for (int off = 1; off < 256; off <<= 1) {
        int t = (tid >= off) ? s[tid - off] : 0;
        __syncthreads();
        s[tid] += t;
        __syncthreads();
    }
    if (i < N) rowptr[i] = s[tid] - v;   // exclusive within block
    if (tid == 255) blocksum[blockIdx.x] = s[255];
}

__global__ __launch_bounds__(512) void k_scan2(int* __restrict__ blocksum, int nb) {
    __shared__ int s[512];
    int tid = threadIdx.x;
    int v = (tid < nb) ? blocksum[tid] : 0;
    s[tid] = v;
    __syncthreads();
#pragma unroll
    for (int off = 1; off < 512; off <<= 1) {
        int t = (tid >= off) ? s[tid - off] : 0;
        __syncthreads();
        s[tid] += t;
        __syncthreads();
    }
    if (tid < nb) blocksum[tid] = s[tid] - v;  // exclusive block offsets
}

__global__ __launch_bounds__(256) void k_scan3(int* __restrict__ rowptr, const int* __restrict__ blocksum,
                                               int N, int total) {
    int i = blockIdx.x * blockDim.x + threadIdx.x;
    if (i < N) rowptr[i] += blocksum[i >> 8];
    if (i == 0) rowptr[N] = total;
}

// ---------------- CSR build: fill col with src per dst ----------------
__global__ __launch_bounds__(256) void k_fill(const int* __restrict__ ei, const int* __restrict__ rowptr,
                                              int* __restrict__ cursor, int* __restrict__ col, int E, int N) {
    int e = blockIdx.x * blockDim.x + threadIdx.x;
    if (e >= E + N) return;
    int src, dst;
    if (e < E) { src = ei[e]; dst = ei[E + e]; }
    else       { src = dst = e - E; }
    int pos = atomicAdd(&cursor[dst], 1);
    col[rowptr[dst] + pos] = src;
}

// ---------------- layer 1 GEMM + alpha (register-tiled 4x4, bf16 h1 out) ----
__global__ __launch_bounds__(256) void k_gemm1(const float* __restrict__ x,
                                               const float* __restrict__ W1,
                                               const float* __restrict__ a_src,
                                               const float* __restrict__ a_dst,
                                               unsigned* __restrict__ h1bf,
                                               float* __restrict__ as1,
                                               float* __restrict__ ad1, int N) {
    int tid = threadIdx.x;
    int c4 = tid & 31;             // cols c4*4 .. c4*4+3
    int rq = tid >> 5;             // 0..7
    int r0 = blockIdx.x * 32 + rq * 4;
    if (r0 >= N) return;
    const float* xr0 = x + (size_t)min(r0 + 0, N - 1) * 64;
    const float* xr1 = x + (size_t)min(r0 + 1, N - 1) * 64;
    const float* xr2 = x + (size_t)min(r0 + 2, N - 1) * 64;
    const float* xr3 = x + (size_t)min(r0 + 3, N - 1) * 64;
    const float4* w4 = (const float4*)W1;   // [64][32] float4

    float4 acc0 = {0,0,0,0}, acc1 = {0,0,0,0}, acc2 = {0,0,0,0}, acc3 = {0,0,0,0};
#pragma unroll
    for (int k4 = 0; k4 < 16; ++k4) {
        float4 xa = *(const float4*)(xr0 + k4 * 4);
        float4 xb = *(const float4*)(xr1 + k4 * 4);
        float4 xc = *(const float4*)(xr2 + k4 * 4);
        float4 xd = *(const float4*)(xr3 + k4 * 4);
        float4 w0 = w4[(k4 * 4 + 0) * 32 + c4];
        float4 w1 = w4[(k4 * 4 + 1) * 32 + c4];
        float4 w2 = w4[(k4 * 4 + 2) * 32 + c4];
        float4 w3 = w4[(k4 * 4 + 3) * 32 + c4];
        acc0.x += xa.x*w0.x + xa.y*w1.x + xa.z*w2.x + xa.w*w3.x;
        acc0.y += xa.x*w0.y + xa.y*w1.y + xa.z*w2.y + xa.w*w3.y;
        acc0.z += xa.x*w0.z + xa.y*w1.z + xa.z*w2.z + xa.w*w3.z;
        acc0.w += xa.x*w0.w + xa.y*w1.w + xa.z*w2.w + xa.w*w3.w;
        acc1.x += xb.x*w0.x + xb.y*w1.x + xb.z*w2.x + xb.w*w3.x;
        acc1.y += xb.x*w0.y + xb.y*w1.y + xb.z*w2.y + xb.w*w3.y;
        acc1.z += xb.x*w0.z + xb.y*w1.z + xb.z*w2.z + xb.w*w3.z;
        acc1.w += xb.x*w0.w + xb.y*w1.w + xb.z*w2.w + xb.w*w3.w;
        acc2.x += xc.x*w0.x + xc.y*w1.x + xc.z*w2.x + xc.w*w3.x;
        acc2.y += xc.x*w0.y + xc.y*w1.y + xc.z*w2.y + xc.w*w3.y;
        acc2.z += xc.x*w0.z + xc.y*w1.z + xc.z*w2.z + xc.w*w3.z;
        acc2.w += xc.x*w0.w + xc.y*w1.w + xc.z*w2.w + xc.w*w3.w;
        acc3.x += xd.x*w0.x + xd.y*w1.x + xd.z*w2.x + xd.w*w3.x;
        acc3.y += xd.x*w0.y + xd.y*w1.y + xd.z*w2.y + xd.w*w3.y;
        acc3.z += xd.x*w0.z + xd.y*w1.z + xd.z*w2.z + xd.w*w3.z;
        acc3.w += xd.x*w0.w + xd.y*w1.w + xd.z*w2.w + xd.w*w3.w;
    }

    // store h1 tile as packed bf16 (row = 64 uints; this thread owns 2 uints)
    uint2 p0 = { bf16pack2(acc0.x, acc0.y), bf16pack2(acc0.z, acc0.w) };
    uint2 p1 = { bf16pack2(acc1.x, acc1.y), bf16pack2(acc1.z, acc1.w) };
    uint2 p2 = { bf16pack2(acc2.x, acc2.y), bf16pack2(acc2.z, acc2.w) };
    uint2 p3 = { bf16pack2(acc3.x, acc3.y), bf16pack2(acc3.z, acc3.w) };
    uint2* hb = (uint2*)h1bf;
    if (r0 + 0 < N) hb[(size_t)(r0 + 0) * 32 + c4] = p0;
    if (r0 + 1 < N) hb[(size_t)(r0 + 1) * 32 + c4] = p1;
    if (r0 + 2 < N) hb[(size_t)(r0 + 2) * 32 + c4] = p2;
    if (r0 + 3 < N) hb[(size_t)(r0 + 3) * 32 + c4] = p3;

    // attention dots from fp32 accumulators (precision unchanged)
    float4 av = ((const float4*)a_src)[c4];
    float4 dv = ((const float4*)a_dst)[c4];
    float s0 = acc0.x*av.x + acc0.y*av.y + acc0.z*av.z + acc0.w*av.w;
    float s1 = acc1.x*av.x + acc1.y*av.y + acc1.z*av.z + acc1.w*av.w;
    float s2 = acc2.x*av.x + acc2.y*av.y + acc2.z*av.z + acc2.w*av.w;
    float s3 = acc3.x*av.x + acc3.y*av.y + acc3.z*av.z + acc3.w*av.w;
    float d0 = acc0.x*dv.x + acc0.y*dv.y + acc0.z*dv.z + acc0.w*dv.w;
    float d1 = acc1.x*dv.x + acc1.y*dv.y + acc1.z*dv.z + acc1.w*dv.w;
    float d2 = acc2.x*dv.x + acc2.y*dv.y + acc2.z*dv.z + acc2.w*dv.w;
    float d3 = acc3.x*dv.x + acc3.y*dv.y + acc3.z*dv.z + acc3.w*dv.w;
#pragma unroll
    for (int off = 1; off < 8; off <<= 1) {
        s0 += __shfl_xor(s0, off); s1 += __shfl_xor(s1, off);
        s2 += __shfl_xor(s2, off); s3 += __shfl_xor(s3, off);
        d0 += __shfl_xor(d0, off); d1 += __shfl_xor(d1, off);
        d2 += __shfl_xor(d2, off); d3 += __shfl_xor(d3, off);
    }
    if ((c4 & 7) == 0) {
        int h = c4 >> 3;
        if (r0 + 0 < N) { as1[(r0 + 0) * 4 + h] = s0; ad1[(r0 + 0) * 4 + h] = d0; }
        if (r0 + 1 < N) { as1[(r0 + 1) * 4 + h] = s1; ad1[(r0 + 1) * 4 + h] = d1; }
        if (r0 + 2 < N) { as1[(r0 + 2) * 4 + h] = s2; ad1[(r0 + 2) * 4 + h] = d2; }
        if (r0 + 3 < N) { as1[(r0 + 3) * 4 + h] = s3; ad1[(r0 + 3) * 4 + h] = d3; }
    }
}

// ---------------- layer 1 fused gather (paired features, bf16 h1, 4x unroll)
// one 64-lane wave per dst; lane owns features 2*lane, 2*lane+1 (same head
// h = lane>>4). den is identical across each 16-lane head group -> no shfl.
__global__ __launch_bounds__(256) void k_gather1(const int* __restrict__ rowptr,
                                                 const int* __restrict__ col,
                                                 const float* __restrict__ as1,
                                                 const float* __restrict__ ad1,
                                                 const unsigned* __restrict__ h1bf,
                                                 const float* __restrict__ b1,
                                                 float* __restrict__ out1, int N) {
    int tid = threadIdx.x;
    int wid = (blockIdx.x * blockDim.x + tid) >> 6;
    if (wid >= N) return;
    int lane = tid & 63;
    int dst = wid;
    int start = rowptr[dst], end = rowptr[dst + 1];
    float4 ad = *(const float4*)(ad1 + (size_t)dst * 4);

    // pass 1: per-head max, edge-strided across lanes
    float m0 = -INFINITY, m1 = -INFINITY, m2 = -INFINITY, m3 = -INFINITY;
    for (int j = start + lane; j < end; j += 64) {
        int src = col[j];
        float4 a = *(const float4*)(as1 + (size_t)src * 4);
        m0 = fmaxf(m0, leaky(a.x + ad.x));
        m1 = fmaxf(m1, leaky(a.y + ad.y));
        m2 = fmaxf(m2, leaky(a.z + ad.z));
        m3 = fmaxf(m3, leaky(a.w + ad.w));
    }
#pragma unroll
    for (int off = 32; off; off >>= 1) {
        m0 = fmaxf(m0, __shfl_xor(m0, off));
        m1 = fmaxf(m1, __shfl_xor(m1, off));
        m2 = fmaxf(m2, __shfl_xor(m2, off));
        m3 = fmaxf(m3, __shfl_xor(m3, off));
    }

    int h = lane >> 4;                       // 0..3
    float mh  = (h == 0) ? m0 : (h == 1) ? m1 : (h == 2) ? m2 : m3;
    float adh = (h == 0) ? ad.x : (h == 1) ? ad.y : (h == 2) ? ad.z : ad.w;

    // pass 2: feature-parallel accumulation, 4 edges per iteration for MLP
    float acc0 = 0.0f, acc1 = 0.0f, den = 0.0f;
    int j = start;
    for (; j + 3 < end; j += 4) {
        int s0 = col[j], s1 = col[j + 1], s2 = col[j + 2], s3 = col[j + 3];
        float a0 = as1[s0 * 4 + h];
        float a1 = as1[s1 * 4 + h];
        float a2 = as1[s2 * 4 + h];
        float a3 = as1[s3 * 4 + h];
        unsigned u0 = h1bf[(size_t)s0 * 64 + lane];
        unsigned u1 = h1bf[(size_t)s1 * 64 + lane];
        unsigned u2 = h1bf[(size_t)s2 * 64 + lane];
        unsigned u3 = h1bf[(size_t)s3 * 64 + lane];
        float x0 = __expf(leaky(a0 + adh) - mh);
        float x1 = __expf(leaky(a1 + adh) - mh);
        float x2 = __expf(leaky(a2 + adh) - mh);
        float x3 = __expf(leaky(a3 + adh) - mh);
        den += (x0 + x1) + (x2 + x3);
        acc0 += x0 * bf16lo(u0) + x1 * bf16lo(u1) + x2 * bf16lo(u2) + x3 * bf16lo(u3);
        acc1 += x0 * bf16hi(u0) + x1 * bf16hi(u1) + x2 * bf16hi(u2) + x3 * bf16hi(u3);
    }
    for (; j < end; ++j) {
        int src = col[j];
        float ex = __expf(leaky(as1[src * 4 + h] + adh) - mh);
        unsigned u = h1bf[(size_t)src * 64 + lane];
        den += ex;
        acc0 += ex * bf16lo(u);
        acc1 += ex * bf16hi(u);
    }

    float inv = 1.0f / (den + EPS);
    int f0 = 2 * lane;
    float vA = acc0 * inv + b1[f0];
    float vB = acc1 * inv + b1[f0 + 1];
    float2 o;
    o.x = vA > 0.0f ? vA : 0.0f;
    o.y = vB > 0.0f ? vB : 0.0f;
    *(float2*)(out1 + (size_t)dst * 128 + f0) = o;
}

// ---------------- layer 2 GEMM + alpha (register-tiled 4x4, bf16 h2 out) ---
__global__ __launch_bounds__(256) void k_gemm2(const float* __restrict__ out1,
                                               const float* __restrict__ W2,
                                               const float* __restrict__ a_src,
                                               const float* __restrict__ a_dst,
                                               unsigned* __restrict__ h2bf,
                                               float* __restrict__ as2,
                                               float* __restrict__ ad2, int N) {
    int tid = threadIdx.x;
    int c4 = tid & 7;              // cols c4*4 .. c4*4+3
    int rq = tid >> 3;             // 0..31
    int r0 = blockIdx.x * 128 + rq * 4;
    if (r0 >= N) return;
    const float* xr0 = out1 + (size_t)min(r0 + 0, N - 1) * 128;
    const float* xr1 = out1 + (size_t)min(r0 + 1, N - 1) * 128;
    const float* xr2 = out1 + (size_t)min(r0 + 2, N - 1) * 128;
    const float* xr3 = out1 + (size_t)min(r0 + 3, N - 1) * 128;
    const float4* w4 = (const float4*)W2;   // [128][8] float4

    float4 acc0 = {0,0,0,0}, acc1 = {0,0,0,0}, acc2 = {0,0,0,0}, acc3 = {0,0,0,0};
#pragma unroll 8
    for (int k4 = 0; k4 < 32; ++k4) {
        float4 xa = *(const float4*)(xr0 + k4 * 4);
        float4 xb = *(const float4*)(xr1 + k4 * 4);
        float4 xc = *(const float4*)(xr2 + k4 * 4);
        float4 xd = *(const float4*)(xr3 + k4 * 4);
        float4 w0 = w4[(k4 * 4 + 0) * 8 + c4];
        float4 w1 = w4[(k4 * 4 + 1) * 8 + c4];
        float4 w2 = w4[(k4 * 4 + 2) * 8 + c4];
        float4 w3 = w4[(k4 * 4 + 3) * 8 + c4];
        acc0.x += xa.x*w0.x + xa.y*w1.x + xa.z*w2.x + xa.w*w3.x;
        acc0.y += xa.x*w0.y + xa.y*w1.y + xa.z*w2.y + xa.w*w3.y;
        acc0.z += xa.x*w0.z + xa.y*w1.z + xa.z*w2.z + xa.w*w3.z;
        acc0.w += xa.x*w0.w + xa.y*w1.w + xa.z*w2.w + xa.w*w3.w;
        acc1.x += xb.x*w0.x + xb.y*w1.x + xb.z*w2.x + xb.w*w3.x;
        acc1.y += xb.x*w0.y + xb.y*w1.y + xb.z*w2.y + xb.w*w3.y;
        acc1.z += xb.x*w0.z + xb.y*w1.z + xb.z*w2.z + xb.w*w3.z;
        acc1.w += xb.x*w0.w + xb.y*w1.w + xb.z*w2.w + xb.w*w3.w;
        acc2.x += xc.x*w0.x + xc.y*w1.x + xc.z*w2.x + xc.w*w3.x;
        acc2.y += xc.x*w0.y + xc.y*w1.y + xc.z*w2.y + xc.w*w3.y;
        acc2.z += xc.x*w0.z + xc.y*w1.z + xc.z*w2.z + xc.w*w3.z;
        acc2.w += xc.x*w0.w + xc.y*w1.w + xc.z*w2.w + xc.w*w3.w;
        acc3.x += xd.x*w0.x + xd.y*w1.x + xd.z*w2.x + xd.w*w3.x;
        acc3.y += xd.x*w0.y + xd.y*w1.y + xd.z*w2.y + xd.w*w3.y;
        acc3.z += xd.x*w0.z + xd.y*w1.z + xd.z*w2.z + xd.w*w3.z;
        acc3.w += xd.x*w0.w + xd.y*w1.w + xd.z*w2.w + xd.w*w3.w;
    }

    // store h2 as packed bf16 (row = 16 uints = 8 uint2; this thread owns uint2 #c4)
    uint2 q0 = { bf16pack2(acc0.x, acc0.y), bf16pack2(acc0.z, acc0.w) };
    uint2 q1 = { bf16pack2(acc1.x, acc1.y), bf16pack2(acc1.z, acc1.w) };
    uint2 q2 = { bf16pack2(acc2.x, acc2.y), bf16pack2(acc2.z, acc2.w) };
    uint2 q3 = { bf16pack2(acc3.x, acc3.y), bf16pack2(acc3.z, acc3.w) };
    uint2* hb = (uint2*)h2bf;
    if (r0 + 0 < N) hb[(size_t)(r0 + 0) * 8 + c4] = q0;
    if (r0 + 1 < N) hb[(size_t)(r0 + 1) * 8 + c4] = q1;
    if (r0 + 2 < N) hb[(size_t)(r0 + 2) * 8 + c4] = q2;
    if (r0 + 3 < N) hb[(size_t)(r0 + 3) * 8 + c4] = q3;

    float4 av = ((const float4*)a_src)[c4];
    float4 dv = ((const float4*)a_dst)[c4];
    float s0 = acc0.x*av.x + acc0.y*av.y + acc0.z*av.z + acc0.w*av.w;
    float s1 = acc1.x*av.x + acc1.y*av.y + acc1.z*av.z + acc1.w*av.w;
    float s2 = acc2.x*av.x + acc2.y*av.y + acc2.z*av.z + acc2.w*av.w;
    float s3 = acc3.x*av.x + acc3.y*av.y + acc3.z*av.z + acc3.w*av.w;
    float d0 = acc0.x*dv.x + acc0.y*dv.y + acc0.z*dv.z + acc0.w*dv.w;
    float d1 = acc1.x*dv.x + acc1.y*dv.y + acc1.z*dv.z + acc1.w*dv.w;
    float d2 = acc2.x*dv.x + acc2.y*dv.y + acc2.z*dv.z + acc2.w*dv.w;
    float d3 = acc3.x*dv.x + acc3.y*dv.y + acc3.z*dv.z + acc3.w*dv.w;
#pragma unroll
    for (int off = 1; off < 8; off <<= 1) {
        s0 += __shfl_xor(s0, off); s1 += __shfl_xor(s1, off);
        s2 += __shfl_xor(s2, off); s3 += __shfl_xor(s3, off);
        d0 += __shfl_xor(d0, off); d1 += __shfl_xor(d1, off);
        d2 += __shfl_xor(d2, off); d3 += __shfl_xor(d3, off);
    }
    if (c4 == 0) {
        if (r0 + 0 < N) { as2[r0 + 0] = s0; ad2[r0 + 0] = d0; }
        if (r0 + 1 < N) { as2[r0 + 1] = s1; ad2[r0 + 1] = d1; }
        if (r0 + 2 < N) { as2[r0 + 2] = s2; ad2[r0 + 2] = d2; }
        if (r0 + 3 < N) { as2[r0 + 3] = s3; ad2[r0 + 3] = d3; }
    }
}

// ---------------- layer 2 fused gather + final linear (feature-parallel) ---
// one 32-lane subwave per dst; lane owns feature c (1 head -> den is
// lane-uniform, no shuffles). 4x edge unroll for MLP. h2 in bf16 (64 B rows).
__global__ __launch_bounds__(256) void k_gather2(const int* __restrict__ rowptr,
                                                 const int* __restrict__ col,
                                                 const float* __restrict__ as2,
                                                 const float* __restrict__ ad2,
                                                 const unsigned short* __restrict__ h2b,
                                                 const float* __restrict__ b2,
                                                 const float* __restrict__ W_lin,
                                                 const float* __restrict__ b_lin,
                                                 float* __restrict__ out, int N) {
    int tid = threadIdx.x;
    int swid = (blockIdx.x * blockDim.x + tid) >> 5;
    if (swid >= N) return;
    int c = tid & 31;
    int dst = swid;
    int start = rowptr[dst], end = rowptr[dst + 1];
    float adv = ad2[dst];

    // pass 1: max, edge-strided across 32 lanes
    float m = -INFINITY;
    for (int j = start + c; j < end; j += 32) {
        m = fmaxf(m, leaky(as2[col[j]] + adv));
    }
#pragma unroll
    for (int off = 16; off; off >>= 1) m = fmaxf(m, __shfl_xor(m, off, 32));

    // pass 2: feature-parallel accumulation, 4 edges per iteration
    float acc = 0.0f, den = 0.0f;
    int j = start;
    for (; j + 3 < end; j += 4) {
        int s0 = col[j], s1 = col[j + 1], s2 = col[j + 2], s3 = col[j + 3];
        float a0 = as2[s0], a1 = as2[s1], a2 = as2[s2], a3 = as2[s3];
        unsigned short u0 = h2b[(size_t)s0 * 32 + c];
        unsigned short u1 = h2b[(size_t)s1 * 32 + c];
        unsigned short u2 = h2b[(size_t)s2 * 32 + c];
        unsigned short u3 = h2b[(size_t)s3 * 32 + c];
        float x0 = __expf(leaky(a0 + adv) - m);
        float x1 = __expf(leaky(a1 + adv) - m);
        float x2 = __expf(leaky(a2 + adv) - m);
        float x3 = __expf(leaky(a3 + adv) - m);
        den += (x0 + x1) + (x2 + x3);
        acc += x0 * __uint_as_float(((unsigned)u0) << 16)
             + x1 * __uint_as_float(((unsigned)u1) << 16)
             + x2 * __uint_as_float(((unsigned)u2) << 16)
             + x3 * __uint_as_float(((unsigned)u3) << 16);
    }
    for (; j < end; ++j) {
        int src = col[j];
        float ex = __expf(leaky(as2[src] + adv) - m);
        unsigned short u = h2b[(size_t)src * 32 + c];
        den += ex;
        acc += ex * __uint_as_float(((unsigned)u) << 16);
    }

    float v = acc / (den + EPS) + b2[c];
    v = v > 0.0f ? v : 0.0f;

    // final linear: dot(v, W_lin) + b_lin
    float w = v * W_lin[c];
#pragma unroll
    for (int off = 16; off; off >>= 1) w += __shfl_xor(w, off, 32);
    if (c == 0) out[dst] = w + b_lin[0];
}

extern "C" void kernel_launch(void* const* d_in, const int* in_sizes, int n_in,
                              void* d_out, int out_size, void* d_ws, size_t ws_size,
                              hipStream_t stream) {
    const float* x      = (const float*)d_in[0];
    const int*   ei     = (const int*)d_in[1];
    // d_in[2] = batch (unused)
    const float* W1     = (const float*)d_in[3];
    const float* a_src1 = (const float*)d_in[4];
    const float* a_dst1 = (const float*)d_in[5];
    const float* b1     = (const float*)d_in[6];
    const float* W2     = (const float*)d_in[7];
    const float* a_src2 = (const float*)d_in[8];
    const float* a_dst2 = (const float*)d_in[9];
    const float* b2     = (const float*)d_in[10];
    const float* W_lin  = (const float*)d_in[11];
    const float* b_lin  = (const float*)d_in[12];
    float* out = (float*)d_out;

    const int N = in_sizes[0] / 64;
    const int E = in_sizes[1] / 2;
    const int T = E + N;               // total edges incl. self-loops
    const int NB = (N + 255) / 256;    // scan blocks

    // workspace layout
    float* ws = (float*)d_ws;
    size_t off = 0;
    float* h1reg = ws + off; off += (size_t)N * 128;  // h1bf (N*64 uints); h2bf (N*16 uints) reuses it
    float* out1 = ws + off; off += (size_t)N * 128;
    float* as1  = ws + off; off += (size_t)N * 4;
    float* ad1  = ws + off; off += (size_t)N * 4;
    float* as2  = ws + off; off += (size_t)N;
    float* ad2  = ws + off; off += (size_t)N;
    int* deg      = (int*)(ws + off); off += (size_t)N;
    int* cursor   = (int*)(ws + off); off += (size_t)N;
    int* rowptr   = (int*)(ws + off); off += (size_t)N + 4;
    int* blocksum = (int*)(ws + off); off += 1024;
    int* colarr   = (int*)(ws + off); off += (size_t)T;
    unsigned* h1bf = (unsigned*)h1reg;   // N*64 uints (bf16x2)
    unsigned* h2bf = (unsigned*)h1reg;   // layer-1 h1 dead after k_gather1; N*16 uints

    const int B = 256;
    auto blocks = [](size_t t, int b) { return (unsigned)((t + b - 1) / b); };

    // CSR build
    k_init <<<blocks(N, B), B, 0, stream>>>(deg, cursor, N);
    k_hist <<<blocks(E, B), B, 0, stream>>>(ei, deg, E);
    k_scan1<<<NB, 256, 0, stream>>>(deg, rowptr, blocksum, N);
    k_scan2<<<1, 512, 0, stream>>>(blocksum, NB);
    k_scan3<<<blocks(N, B), B, 0, stream>>>(rowptr, blocksum, N, T);
    k_fill <<<blocks(T, B), B, 0, stream>>>(ei, rowptr, cursor, colarr, E, N);

    // layer 1
    k_gemm1  <<<(unsigned)((N + 31) / 32), B, 0, stream>>>(x, W1, a_src1, a_dst1, h1bf, as1, ad1, N);
    k_gather1<<<blocks((size_t)N * 64, B), B, 0, stream>>>(rowptr, colarr, as1, ad1, h1bf, b1, out1, N);

    // layer 2 (+ fused final linear)
    k_gemm2  <<<(unsigned)((N + 127) / 128), B, 0, stream>>>(out1, W2, a_src2, a_dst2, h2bf, as2, ad2, N);
    k_gather2<<<blocks((size_t)N * 32, B), B, 0, stream>>>(rowptr, colarr, as2, ad2,
                                                           (const unsigned short*)h2bf, b2, W_lin, b_lin, out, N);
}

// Round 8
// 452.982 us; speedup vs baseline: 1.4812x; 1.2040x over previous
//
#include <hip/hip_runtime.h>
#include <math.h>

#define NEG_SLOPE 0.2f
#define EPS 1e-16f

__device__ inline float leaky(float v) {
    return v >= 0.0f ? v : NEG_SLOPE * v;
}

// pack two floats into bf16x2 (RNE), low half = first arg
__device__ inline unsigned bf16pack2(float a, float b) {
    unsigned ua = __float_as_uint(a);
    unsigned ub = __float_as_uint(b);
    ua = (ua + 0x7FFFu + ((ua >> 16) & 1u)) >> 16;
    ub = (ub + 0x7FFFu + ((ub >> 16) & 1u)) >> 16;
    return ua | (ub << 16);
}

__device__ inline float bf16lo(unsigned u) { return __uint_as_float(u << 16); }
__device__ inline float bf16hi(unsigned u) { return __uint_as_float(u & 0xFFFF0000u); }

// ---------------- init: deg=1 (self-loop pre-counted), cursor=0 ----------------
__global__ __launch_bounds__(256) void k_init(int* deg, int* cursor, int N) {
    int gid = blockIdx.x * blockDim.x + threadIdx.x;
    if (gid < N) { deg[gid] = 1; cursor[gid] = 0; }
}

// ---------------- CSR build: histogram of dst ----------------
__global__ __launch_bounds__(256) void k_hist(const int* __restrict__ ei, int* __restrict__ deg, int E) {
    int e = blockIdx.x * blockDim.x + threadIdx.x;
    if (e < E) atomicAdd(&deg[ei[E + e]], 1);
}

// ---------------- CSR build: hierarchical exclusive scan ----------------
__global__ __launch_bounds__(256) void k_scan1(const int* __restrict__ deg, int* __restrict__ rowptr,
                                               int* __restrict__ blocksum, int N) {
    __shared__ int s[256];
    int tid = threadIdx.x;
    int i = blockIdx.x * 256 + tid;
    int v = (i < N) ? deg[i] : 0;
    s[tid] = v;
    __syncthreads();
#pragma unroll
    for (int off = 1; off < 256; off <<= 1) {
        int t = (tid >= off) ? s[tid - off] : 0;
        __syncthreads();
        s[tid] += t;
        __syncthreads();
    }
    if (i < N) rowptr[i] = s[tid] - v;   // exclusive within block
    if (tid == 255) blocksum[blockIdx.x] = s[255];
}

__global__ __launch_bounds__(512) void k_scan2(int* __restrict__ blocksum, int nb) {
    __shared__ int s[512];
    int tid = threadIdx.x;
    int v = (tid < nb) ? blocksum[tid] : 0;
    s[tid] = v;
    __syncthreads();
#pragma unroll
    for (int off = 1; off < 512; off <<= 1) {
        int t = (tid >= off) ? s[tid - off] : 0;
        __syncthreads();
        s[tid] += t;
        __syncthreads();
    }
    if (tid < nb) blocksum[tid] = s[tid] - v;  // exclusive block offsets
}

__global__ __launch_bounds__(256) void k_scan3(int* __restrict__ rowptr, const int* __restrict__ blocksum,
                                               int N, int total) {
    int i = blockIdx.x * blockDim.x + threadIdx.x;
    if (i < N) rowptr[i] += blocksum[i >> 8];
    if (i == 0) rowptr[N] = total;
}

// ---------------- CSR build: fill col with src per dst ----------------
__global__ __launch_bounds__(256) void k_fill(const int* __restrict__ ei, const int* __restrict__ rowptr,
                                              int* __restrict__ cursor, int* __restrict__ col, int E, int N) {
    int e = blockIdx.x * blockDim.x + threadIdx.x;
    if (e >= E + N) return;
    int src, dst;
    if (e < E) { src = ei[e]; dst = ei[E + e]; }
    else       { src = dst = e - E; }
    int pos = atomicAdd(&cursor[dst], 1);
    col[rowptr[dst] + pos] = src;
}

// ---------------- layer 1 GEMM + alpha (LDS-staged W1 + x tile) ----------
// block = 256 threads, tile 32 rows x 128 cols. W1 (32 KB) and x tile (8 KB)
// staged in LDS; K-loop reads only LDS -> low VGPR, high occupancy.
__global__ __launch_bounds__(256) void k_gemm1(const float* __restrict__ x,
                                               const float* __restrict__ W1,
                                               const float* __restrict__ a_src,
                                               const float* __restrict__ a_dst,
                                               unsigned* __restrict__ h1bf,
                                               float* __restrict__ as1,
                                               float* __restrict__ ad1, int N) {
    __shared__ float sW[64 * 128];   // 32 KB, [k][col]
    __shared__ float sX[32 * 64];    // 8 KB,  [row][k]
    int tid = threadIdx.x;
    int block_r0 = blockIdx.x * 32;

    // stage W1: 2048 float4, 8 per thread (coalesced)
    {
        float4* dst = (float4*)sW;
        const float4* srcp = (const float4*)W1;
#pragma unroll
        for (int i = 0; i < 8; ++i) dst[tid + 256 * i] = srcp[tid + 256 * i];
    }
    // stage x tile: 512 float4, 2 per thread
    {
        float4* dst = (float4*)sX;
#pragma unroll
        for (int i = 0; i < 2; ++i) {
            int idx = tid + 256 * i;
            int r = idx >> 4;            // 0..31
            int c = idx & 15;            // float4 within row
            int gr = min(block_r0 + r, N - 1);
            dst[idx] = ((const float4*)(x + (size_t)gr * 64))[c];
        }
    }
    __syncthreads();

    int c4 = tid & 31;             // col quad 0..31
    int rq = tid >> 5;             // row quad 0..7
    int r0 = block_r0 + rq * 4;
    const float4* wS = (const float4*)sW;   // [64][32]
    const float4* xS = (const float4*)sX;   // [32][16]

    float4 acc0 = {0,0,0,0}, acc1 = {0,0,0,0}, acc2 = {0,0,0,0}, acc3 = {0,0,0,0};
#pragma unroll 2
    for (int k4 = 0; k4 < 16; ++k4) {
        float4 xa = xS[(rq * 4 + 0) * 16 + k4];
        float4 xb = xS[(rq * 4 + 1) * 16 + k4];
        float4 xc = xS[(rq * 4 + 2) * 16 + k4];
        float4 xd = xS[(rq * 4 + 3) * 16 + k4];
        float4 w0 = wS[(k4 * 4 + 0) * 32 + c4];
        float4 w1 = wS[(k4 * 4 + 1) * 32 + c4];
        float4 w2 = wS[(k4 * 4 + 2) * 32 + c4];
        float4 w3 = wS[(k4 * 4 + 3) * 32 + c4];
        acc0.x += xa.x*w0.x + xa.y*w1.x + xa.z*w2.x + xa.w*w3.x;
        acc0.y += xa.x*w0.y + xa.y*w1.y + xa.z*w2.y + xa.w*w3.y;
        acc0.z += xa.x*w0.z + xa.y*w1.z + xa.z*w2.z + xa.w*w3.z;
        acc0.w += xa.x*w0.w + xa.y*w1.w + xa.z*w2.w + xa.w*w3.w;
        acc1.x += xb.x*w0.x + xb.y*w1.x + xb.z*w2.x + xb.w*w3.x;
        acc1.y += xb.x*w0.y + xb.y*w1.y + xb.z*w2.y + xb.w*w3.y;
        acc1.z += xb.x*w0.z + xb.y*w1.z + xb.z*w2.z + xb.w*w3.z;
        acc1.w += xb.x*w0.w + xb.y*w1.w + xb.z*w2.w + xb.w*w3.w;
        acc2.x += xc.x*w0.x + xc.y*w1.x + xc.z*w2.x + xc.w*w3.x;
        acc2.y += xc.x*w0.y + xc.y*w1.y + xc.z*w2.y + xc.w*w3.y;
        acc2.z += xc.x*w0.z + xc.y*w1.z + xc.z*w2.z + xc.w*w3.z;
        acc2.w += xc.x*w0.w + xc.y*w1.w + xc.z*w2.w + xc.w*w3.w;
        acc3.x += xd.x*w0.x + xd.y*w1.x + xd.z*w2.x + xd.w*w3.x;
        acc3.y += xd.x*w0.y + xd.y*w1.y + xd.z*w2.y + xd.w*w3.y;
        acc3.z += xd.x*w0.z + xd.y*w1.z + xd.z*w2.z + xd.w*w3.z;
        acc3.w += xd.x*w0.w + xd.y*w1.w + xd.z*w2.w + xd.w*w3.w;
    }

    // store h1 tile as packed bf16 (row = 64 uints; this thread owns 2 uints)
    uint2 p0 = { bf16pack2(acc0.x, acc0.y), bf16pack2(acc0.z, acc0.w) };
    uint2 p1 = { bf16pack2(acc1.x, acc1.y), bf16pack2(acc1.z, acc1.w) };
    uint2 p2 = { bf16pack2(acc2.x, acc2.y), bf16pack2(acc2.z, acc2.w) };
    uint2 p3 = { bf16pack2(acc3.x, acc3.y), bf16pack2(acc3.z, acc3.w) };
    uint2* hb = (uint2*)h1bf;
    if (r0 + 0 < N) hb[(size_t)(r0 + 0) * 32 + c4] = p0;
    if (r0 + 1 < N) hb[(size_t)(r0 + 1) * 32 + c4] = p1;
    if (r0 + 2 < N) hb[(size_t)(r0 + 2) * 32 + c4] = p2;
    if (r0 + 3 < N) hb[(size_t)(r0 + 3) * 32 + c4] = p3;

    // attention dots from fp32 accumulators
    float4 av = ((const float4*)a_src)[c4];
    float4 dv = ((const float4*)a_dst)[c4];
    float s0 = acc0.x*av.x + acc0.y*av.y + acc0.z*av.z + acc0.w*av.w;
    float s1 = acc1.x*av.x + acc1.y*av.y + acc1.z*av.z + acc1.w*av.w;
    float s2 = acc2.x*av.x + acc2.y*av.y + acc2.z*av.z + acc2.w*av.w;
    float s3 = acc3.x*av.x + acc3.y*av.y + acc3.z*av.z + acc3.w*av.w;
    float d0 = acc0.x*dv.x + acc0.y*dv.y + acc0.z*dv.z + acc0.w*dv.w;
    float d1 = acc1.x*dv.x + acc1.y*dv.y + acc1.z*dv.z + acc1.w*dv.w;
    float d2 = acc2.x*dv.x + acc2.y*dv.y + acc2.z*dv.z + acc2.w*dv.w;
    float d3 = acc3.x*dv.x + acc3.y*dv.y + acc3.z*dv.z + acc3.w*dv.w;
#pragma unroll
    for (int off = 1; off < 8; off <<= 1) {
        s0 += __shfl_xor(s0, off); s1 += __shfl_xor(s1, off);
        s2 += __shfl_xor(s2, off); s3 += __shfl_xor(s3, off);
        d0 += __shfl_xor(d0, off); d1 += __shfl_xor(d1, off);
        d2 += __shfl_xor(d2, off); d3 += __shfl_xor(d3, off);
    }
    if ((c4 & 7) == 0) {
        int h = c4 >> 3;
        if (r0 + 0 < N) { as1[(r0 + 0) * 4 + h] = s0; ad1[(r0 + 0) * 4 + h] = d0; }
        if (r0 + 1 < N) { as1[(r0 + 1) * 4 + h] = s1; ad1[(r0 + 1) * 4 + h] = d1; }
        if (r0 + 2 < N) { as1[(r0 + 2) * 4 + h] = s2; ad1[(r0 + 2) * 4 + h] = d2; }
        if (r0 + 3 < N) { as1[(r0 + 3) * 4 + h] = s3; ad1[(r0 + 3) * 4 + h] = d3; }
    }
}

// ---------------- layer 1 fused gather (paired features, bf16 h1, 4x unroll)
__global__ __launch_bounds__(256) void k_gather1(const int* __restrict__ rowptr,
                                                 const int* __restrict__ col,
                                                 const float* __restrict__ as1,
                                                 const float* __restrict__ ad1,
                                                 const unsigned* __restrict__ h1bf,
                                                 const float* __restrict__ b1,
                                                 float* __restrict__ out1, int N) {
    int tid = threadIdx.x;
    int wid = (blockIdx.x * blockDim.x + tid) >> 6;
    if (wid >= N) return;
    int lane = tid & 63;
    int dst = wid;
    int start = rowptr[dst], end = rowptr[dst + 1];
    float4 ad = *(const float4*)(ad1 + (size_t)dst * 4);

    // pass 1: per-head max, edge-strided across lanes
    float m0 = -INFINITY, m1 = -INFINITY, m2 = -INFINITY, m3 = -INFINITY;
    for (int j = start + lane; j < end; j += 64) {
        int src = col[j];
        float4 a = *(const float4*)(as1 + (size_t)src * 4);
        m0 = fmaxf(m0, leaky(a.x + ad.x));
        m1 = fmaxf(m1, leaky(a.y + ad.y));
        m2 = fmaxf(m2, leaky(a.z + ad.z));
        m3 = fmaxf(m3, leaky(a.w + ad.w));
    }
#pragma unroll
    for (int off = 32; off; off >>= 1) {
        m0 = fmaxf(m0, __shfl_xor(m0, off));
        m1 = fmaxf(m1, __shfl_xor(m1, off));
        m2 = fmaxf(m2, __shfl_xor(m2, off));
        m3 = fmaxf(m3, __shfl_xor(m3, off));
    }

    int h = lane >> 4;                       // 0..3
    float mh  = (h == 0) ? m0 : (h == 1) ? m1 : (h == 2) ? m2 : m3;
    float adh = (h == 0) ? ad.x : (h == 1) ? ad.y : (h == 2) ? ad.z : ad.w;

    // pass 2: feature-parallel accumulation, 4 edges per iteration for MLP
    float acc0 = 0.0f, acc1 = 0.0f, den = 0.0f;
    int j = start;
    for (; j + 3 < end; j += 4) {
        int s0 = col[j], s1 = col[j + 1], s2 = col[j + 2], s3 = col[j + 3];
        float a0 = as1[s0 * 4 + h];
        float a1 = as1[s1 * 4 + h];
        float a2 = as1[s2 * 4 + h];
        float a3 = as1[s3 * 4 + h];
        unsigned u0 = h1bf[(size_t)s0 * 64 + lane];
        unsigned u1 = h1bf[(size_t)s1 * 64 + lane];
        unsigned u2 = h1bf[(size_t)s2 * 64 + lane];
        unsigned u3 = h1bf[(size_t)s3 * 64 + lane];
        float x0 = __expf(leaky(a0 + adh) - mh);
        float x1 = __expf(leaky(a1 + adh) - mh);
        float x2 = __expf(leaky(a2 + adh) - mh);
        float x3 = __expf(leaky(a3 + adh) - mh);
        den += (x0 + x1) + (x2 + x3);
        acc0 += x0 * bf16lo(u0) + x1 * bf16lo(u1) + x2 * bf16lo(u2) + x3 * bf16lo(u3);
        acc1 += x0 * bf16hi(u0) + x1 * bf16hi(u1) + x2 * bf16hi(u2) + x3 * bf16hi(u3);
    }
    for (; j < end; ++j) {
        int src = col[j];
        float ex = __expf(leaky(as1[src * 4 + h] + adh) - mh);
        unsigned u = h1bf[(size_t)src * 64 + lane];
        den += ex;
        acc0 += ex * bf16lo(u);
        acc1 += ex * bf16hi(u);
    }

    float inv = 1.0f / (den + EPS);
    int f0 = 2 * lane;
    float vA = acc0 * inv + b1[f0];
    float vB = acc1 * inv + b1[f0 + 1];
    float2 o;
    o.x = vA > 0.0f ? vA : 0.0f;
    o.y = vB > 0.0f ? vB : 0.0f;
    *(float2*)(out1 + (size_t)dst * 128 + f0) = o;
}

// ---------------- layer 2 GEMM + alpha (LDS-staged W2, bf16 h2 out) --------
// block = 256 threads, tile 128 rows x 32 cols; W2 (16 KB) in LDS; x rows
// from global (8x L1-broadcast redundancy).
__global__ __launch_bounds__(256) void k_gemm2(const float* __restrict__ out1,
                                               const float* __restrict__ W2,
                                               const float* __restrict__ a_src,
                                               const float* __restrict__ a_dst,
                                               unsigned* __restrict__ h2bf,
                                               float* __restrict__ as2,
                                               float* __restrict__ ad2, int N) {
    __shared__ float sW[128 * 32];   // 16 KB, [k][col]
    int tid = threadIdx.x;

    // stage W2: 1024 float4, 4 per thread
    {
        float4* dst = (float4*)sW;
        const float4* srcp = (const float4*)W2;
#pragma unroll
        for (int i = 0; i < 4; ++i) dst[tid + 256 * i] = srcp[tid + 256 * i];
    }
    __syncthreads();

    int c4 = tid & 7;              // col quad 0..7
    int rq = tid >> 3;             // row quad 0..31
    int r0 = blockIdx.x * 128 + rq * 4;
    if (r0 >= N) return;
    const float* xr0 = out1 + (size_t)min(r0 + 0, N - 1) * 128;
    const float* xr1 = out1 + (size_t)min(r0 + 1, N - 1) * 128;
    const float* xr2 = out1 + (size_t)min(r0 + 2, N - 1) * 128;
    const float* xr3 = out1 + (size_t)min(r0 + 3, N - 1) * 128;
    const float4* wS = (const float4*)sW;   // [128][8]

    float4 acc0 = {0,0,0,0}, acc1 = {0,0,0,0}, acc2 = {0,0,0,0}, acc3 = {0,0,0,0};
#pragma unroll 2
    for (int k4 = 0; k4 < 32; ++k4) {
        float4 xa = *(const float4*)(xr0 + k4 * 4);
        float4 xb = *(const float4*)(xr1 + k4 * 4);
        float4 xc = *(const float4*)(xr2 + k4 * 4);
        float4 xd = *(const float4*)(xr3 + k4 * 4);
        float4 w0 = wS[(k4 * 4 + 0) * 8 + c4];
        float4 w1 = wS[(k4 * 4 + 1) * 8 + c4];
        float4 w2 = wS[(k4 * 4 + 2) * 8 + c4];
        float4 w3 = wS[(k4 * 4 + 3) * 8 + c4];
        acc0.x += xa.x*w0.x + xa.y*w1.x + xa.z*w2.x + xa.w*w3.x;
        acc0.y += xa.x*w0.y + xa.y*w1.y + xa.z*w2.y + xa.w*w3.y;
        acc0.z += xa.x*w0.z + xa.y*w1.z + xa.z*w2.z + xa.w*w3.z;
        acc0.w += xa.x*w0.w + xa.y*w1.w + xa.z*w2.w + xa.w*w3.w;
        acc1.x += xb.x*w0.x + xb.y*w1.x + xb.z*w2.x + xb.w*w3.x;
        acc1.y += xb.x*w0.y + xb.y*w1.y + xb.z*w2.y + xb.w*w3.y;
        acc1.z += xb.x*w0.z + xb.y*w1.z + xb.z*w2.z + xb.w*w3.z;
        acc1.w += xb.x*w0.w + xb.y*w1.w + xb.z*w2.w + xb.w*w3.w;
        acc2.x += xc.x*w0.x + xc.y*w1.x + xc.z*w2.x + xc.w*w3.x;
        acc2.y += xc.x*w0.y + xc.y*w1.y + xc.z*w2.y + xc.w*w3.y;
        acc2.z += xc.x*w0.z + xc.y*w1.z + xc.z*w2.z + xc.w*w3.z;
        acc2.w += xc.x*w0.w + xc.y*w1.w + xc.z*w2.w + xc.w*w3.w;
        acc3.x += xd.x*w0.x + xd.y*w1.x + xd.z*w2.x + xd.w*w3.x;
        acc3.y += xd.x*w0.y + xd.y*w1.y + xd.z*w2.y + xd.w*w3.y;
        acc3.z += xd.x*w0.z + xd.y*w1.z + xd.z*w2.z + xd.w*w3.z;
        acc3.w += xd.x*w0.w + xd.y*w1.w + xd.z*w2.w + xd.w*w3.w;
    }

    // store h2 as packed bf16 (row = 16 uints = 8 uint2)
    uint2 q0 = { bf16pack2(acc0.x, acc0.y), bf16pack2(acc0.z, acc0.w) };
    uint2 q1 = { bf16pack2(acc1.x, acc1.y), bf16pack2(acc1.z, acc1.w) };
    uint2 q2 = { bf16pack2(acc2.x, acc2.y), bf16pack2(acc2.z, acc2.w) };
    uint2 q3 = { bf16pack2(acc3.x, acc3.y), bf16pack2(acc3.z, acc3.w) };
    uint2* hb = (uint2*)h2bf;
    if (r0 + 0 < N) hb[(size_t)(r0 + 0) * 8 + c4] = q0;
    if (r0 + 1 < N) hb[(size_t)(r0 + 1) * 8 + c4] = q1;
    if (r0 + 2 < N) hb[(size_t)(r0 + 2) * 8 + c4] = q2;
    if (r0 + 3 < N) hb[(size_t)(r0 + 3) * 8 + c4] = q3;

    float4 av = ((const float4*)a_src)[c4];
    float4 dv = ((const float4*)a_dst)[c4];
    float s0 = acc0.x*av.x + acc0.y*av.y + acc0.z*av.z + acc0.w*av.w;
    float s1 = acc1.x*av.x + acc1.y*av.y + acc1.z*av.z + acc1.w*av.w;
    float s2 = acc2.x*av.x + acc2.y*av.y + acc2.z*av.z + acc2.w*av.w;
    float s3 = acc3.x*av.x + acc3.y*av.y + acc3.z*av.z + acc3.w*av.w;
    float d0 = acc0.x*dv.x + acc0.y*dv.y + acc0.z*dv.z + acc0.w*dv.w;
    float d1 = acc1.x*dv.x + acc1.y*dv.y + acc1.z*dv.z + acc1.w*dv.w;
    float d2 = acc2.x*dv.x + acc2.y*dv.y + acc2.z*dv.z + acc2.w*dv.w;
    float d3 = acc3.x*dv.x + acc3.y*dv.y + acc3.z*dv.z + acc3.w*dv.w;
#pragma unroll
    for (int off = 1; off < 8; off <<= 1) {
        s0 += __shfl_xor(s0, off); s1 += __shfl_xor(s1, off);
        s2 += __shfl_xor(s2, off); s3 += __shfl_xor(s3, off);
        d0 += __shfl_xor(d0, off); d1 += __shfl_xor(d1, off);
        d2 += __shfl_xor(d2, off); d3 += __shfl_xor(d3, off);
    }
    if (c4 == 0) {
        if (r0 + 0 < N) { as2[r0 + 0] = s0; ad2[r0 + 0] = d0; }
        if (r0 + 1 < N) { as2[r0 + 1] = s1; ad2[r0 + 1] = d1; }
        if (r0 + 2 < N) { as2[r0 + 2] = s2; ad2[r0 + 2] = d2; }
        if (r0 + 3 < N) { as2[r0 + 3] = s3; ad2[r0 + 3] = d3; }
    }
}

// ---------------- layer 2 fused gather + final linear (feature-parallel) ---
__global__ __launch_bounds__(256) void k_gather2(const int* __restrict__ rowptr,
                                                 const int* __restrict__ col,
                                                 const float* __restrict__ as2,
                                                 const float* __restrict__ ad2,
                                                 const unsigned short* __restrict__ h2b,
                                                 const float* __restrict__ b2,
                                                 const float* __restrict__ W_lin,
                                                 const float* __restrict__ b_lin,
                                                 float* __restrict__ out, int N) {
    int tid = threadIdx.x;
    int swid = (blockIdx.x * blockDim.x + tid) >> 5;
    if (swid >= N) return;
    int c = tid & 31;
    int dst = swid;
    int start = rowptr[dst], end = rowptr[dst + 1];
    float adv = ad2[dst];

    // pass 1: max, edge-strided across 32 lanes
    float m = -INFINITY;
    for (int j = start + c; j < end; j += 32) {
        m = fmaxf(m, leaky(as2[col[j]] + adv));
    }
#pragma unroll
    for (int off = 16; off; off >>= 1) m = fmaxf(m, __shfl_xor(m, off, 32));

    // pass 2: feature-parallel accumulation, 4 edges per iteration
    float acc = 0.0f, den = 0.0f;
    int j = start;
    for (; j + 3 < end; j += 4) {
        int s0 = col[j], s1 = col[j + 1], s2 = col[j + 2], s3 = col[j + 3];
        float a0 = as2[s0], a1 = as2[s1], a2 = as2[s2], a3 = as2[s3];
        unsigned short u0 = h2b[(size_t)s0 * 32 + c];
        unsigned short u1 = h2b[(size_t)s1 * 32 + c];
        unsigned short u2 = h2b[(size_t)s2 * 32 + c];
        unsigned short u3 = h2b[(size_t)s3 * 32 + c];
        float x0 = __expf(leaky(a0 + adv) - m);
        float x1 = __expf(leaky(a1 + adv) - m);
        float x2 = __expf(leaky(a2 + adv) - m);
        float x3 = __expf(leaky(a3 + adv) - m);
        den += (x0 + x1) + (x2 + x3);
        acc += x0 * __uint_as_float(((unsigned)u0) << 16)
             + x1 * __uint_as_float(((unsigned)u1) << 16)
             + x2 * __uint_as_float(((unsigned)u2) << 16)
             + x3 * __uint_as_float(((unsigned)u3) << 16);
    }
    for (; j < end; ++j) {
        int src = col[j];
        float ex = __expf(leaky(as2[src] + adv) - m);
        unsigned short u = h2b[(size_t)src * 32 + c];
        den += ex;
        acc += ex * __uint_as_float(((unsigned)u) << 16);
    }

    float v = acc / (den + EPS) + b2[c];
    v = v > 0.0f ? v : 0.0f;

    // final linear: dot(v, W_lin) + b_lin
    float w = v * W_lin[c];
#pragma unroll
    for (int off = 16; off; off >>= 1) w += __shfl_xor(w, off, 32);
    if (c == 0) out[dst] = w + b_lin[0];
}

extern "C" void kernel_launch(void* const* d_in, const int* in_sizes, int n_in,
                              void* d_out, int out_size, void* d_ws, size_t ws_size,
                              hipStream_t stream) {
    const float* x      = (const float*)d_in[0];
    const int*   ei     = (const int*)d_in[1];
    // d_in[2] = batch (unused)
    const float* W1     = (const float*)d_in[3];
    const float* a_src1 = (const float*)d_in[4];
    const float* a_dst1 = (const float*)d_in[5];
    const float* b1     = (const float*)d_in[6];
    const float* W2     = (const float*)d_in[7];
    const float* a_src2 = (const float*)d_in[8];
    const float* a_dst2 = (const float*)d_in[9];
    const float* b2     = (const float*)d_in[10];
    const float* W_lin  = (const float*)d_in[11];
    const float* b_lin  = (const float*)d_in[12];
    float* out = (float*)d_out;

    const int N = in_sizes[0] / 64;
    const int E = in_sizes[1] / 2;
    const int T = E + N;               // total edges incl. self-loops
    const int NB = (N + 255) / 256;    // scan blocks

    // workspace layout
    float* ws = (float*)d_ws;
    size_t off = 0;
    float* h1reg = ws + off; off += (size_t)N * 128;  // h1bf (N*64 uints); h2bf (N*16 uints) reuses it
    float* out1 = ws + off; off += (size_t)N * 128;
    float* as1  = ws + off; off += (size_t)N * 4;
    float* ad1  = ws + off; off += (size_t)N * 4;
    float* as2  = ws + off; off += (size_t)N;
    float* ad2  = ws + off; off += (size_t)N;
    int* deg      = (int*)(ws + off); off += (size_t)N;
    int* cursor   = (int*)(ws + off); off += (size_t)N;
    int* rowptr   = (int*)(ws + off); off += (size_t)N + 4;
    int* blocksum = (int*)(ws + off); off += 1024;
    int* colarr   = (int*)(ws + off); off += (size_t)T;
    unsigned* h1bf = (unsigned*)h1reg;   // N*64 uints (bf16x2)
    unsigned* h2bf = (unsigned*)h1reg;   // layer-1 h1 dead after k_gather1; N*16 uints

    const int B = 256;
    auto blocks = [](size_t t, int b) { return (unsigned)((t + b - 1) / b); };

    // CSR build
    k_init <<<blocks(N, B), B, 0, stream>>>(deg, cursor, N);
    k_hist <<<blocks(E, B), B, 0, stream>>>(ei, deg, E);
    k_scan1<<<NB, 256, 0, stream>>>(deg, rowptr, blocksum, N);
    k_scan2<<<1, 512, 0, stream>>>(blocksum, NB);
    k_scan3<<<blocks(N, B), B, 0, stream>>>(rowptr, blocksum, N, T);
    k_fill <<<blocks(T, B), B, 0, stream>>>(ei, rowptr, cursor, colarr, E, N);

    // layer 1
    k_gemm1  <<<(unsigned)((N + 31) / 32), B, 0, stream>>>(x, W1, a_src1, a_dst1, h1bf, as1, ad1, N);
    k_gather1<<<blocks((size_t)N * 64, B), B, 0, stream>>>(rowptr, colarr, as1, ad1, h1bf, b1, out1, N);

    // layer 2 (+ fused final linear)
    k_gemm2  <<<(unsigned)((N + 127) / 128), B, 0, stream>>>(out1, W2, a_src2, a_dst2, h2bf, as2, ad2, N);
    k_gather2<<<blocks((size_t)N * 32, B), B, 0, stream>>>(rowptr, colarr, as2, ad2,
                                                           (const unsigned short*)h2bf, b2, W_lin, b_lin, out, N);
}